// Round 7
// baseline (42.718 us; speedup 1.0000x reference)
//
#include <hip/hip_runtime.h>
#include <math.h>

#define BTOT 262144
#define R 3
#define F 4
#define H 16
#define A 18
#define SMALL_NUM_F 0.015f
#define MARGIN_TAU 1e-4f

// ws layout: [0..767] header (int counter at index 0), list of u32 at +768B
#define WS_COUNT 0
#define WS_HDR_BYTES 768

// ---------------------------------------------------------------------------
// Exact f32 chain — verbatim round-1 (measured absmax 0 in rounds 1/5/6).
// ---------------------------------------------------------------------------
__device__ __forceinline__ void compute_m_exact(
    const float sf[F],
    const float* __restrict__ W1, const float* __restrict__ b1,
    const float* __restrict__ W2, const float* __restrict__ b2,
    const float* __restrict__ W3, const float* __restrict__ b3,
    float m[R][F])
{
#pragma unroll
    for (int r = 0; r < R; ++r) {
#pragma unroll
        for (int f = 0; f < F; ++f) {
            const int rf = r * F + f;
            const float* w1  = W1 + rf * H;
            const float* bb1 = b1 + rf * H;
            const float* w2  = W2 + rf * H * H;
            const float* bb2 = b2 + rf * H;
            const float* w3  = W3 + rf * H;
            float h1[H];
#pragma unroll
            for (int h = 0; h < H; ++h) {
                float v = fmaf(sf[f], w1[h], bb1[h]);
                h1[h] = fmaxf(v, 0.01f * v);
            }
            float acc[H];
#pragma unroll
            for (int o = 0; o < H; ++o) acc[o] = bb2[o];
#pragma unroll
            for (int h = 0; h < H; ++h) {
                const float hv = h1[h];
#pragma unroll
                for (int o = 0; o < H; ++o)
                    acc[o] = fmaf(hv, w2[h * H + o], acc[o]);
            }
            float dot = b3[rf];
#pragma unroll
            for (int o = 0; o < H; ++o) {
                float v = fmaxf(acc[o], 0.01f * acc[o]);
                dot = fmaf(v, w3[o], dot);
            }
            float mm = 1.0f / (1.0f + expf(-dot));
            m[r][f] = fmaxf(mm, SMALL_NUM_F);
        }
    }
}

__device__ __forceinline__ void compute_strength_exact(
    const float m[R][F], const float g[R][F], const float cond[R], float st[R])
{
#pragma unroll
    for (int r = 0; r < R; ++r) {
        const bool c = cond[r] != 0.0f;
        float X[F];
        float ssum = 0.f;
#pragma unroll
        for (int f = 0; f < F; ++f) {
            float gv = g[r][f];
            float xw = expf(0.1f * (gv / m[r][f]));
            if (c) xw *= gv;
            X[f] = xw;
            ssum += xw;
        }
        float sv = 0.f;
#pragma unroll
        for (int f = 0; f < F; ++f)
            sv += m[r][f] * (X[f] / ssum) * g[r][f];
        st[r] = isnan(sv) ? 0.0f : sv;
    }
}

__device__ __forceinline__ int path_argmax(const float st[R]) {
    const float r0 = st[0], r1 = st[1], r2 = st[2];
    const float p0 = r0 * r1;
    const float p1 = r0 * (1.0f - r1);
    const float p2 = (1.0f - r0) * r2;
    const float p3 = (1.0f - r0) * (1.0f - r2);
    int idx = 0;
    float best = p0;
    if (p1 > best) { best = p1; idx = 1; }
    if (p2 > best) { best = p2; idx = 2; }
    if (p3 > best) { best = p3; idx = 3; }
    return idx;
}

// gumbel-softmax hard selection + leaves softmax + cond — verbatim round-1
// float ops; computed redundantly per block (deterministic, identical).
__device__ __forceinline__ void block_compute_gumbel_leaves(
    const float* __restrict__ p_select, const float* __restrict__ gumbel,
    const float* __restrict__ leaves, const float* __restrict__ b3,
    int tid, float* shG, float* shB3, float* shCond, float2 (*shL2)[9])
{
    if (tid < R * F) {
        const int rf = tid;
        float l0 = p_select[rf * 2 + 0] + gumbel[rf * 2 + 0];
        float l1 = p_select[rf * 2 + 1] + gumbel[rf * 2 + 1];
        float mx = fmaxf(l0, l1);
        float e0 = expf(l0 - mx), e1 = expf(l1 - mx);
        float den = e0 + e1;
        float y0 = e0 / den, y1 = e1 / den;
        float ym = fmaxf(y0, y1);
        shG[rf] = (y1 == ym) ? 1.0f : 0.0f;
        shB3[rf] = b3[rf];
    }
    if (tid < 4) {
        float mx = leaves[tid * A];
        for (int a = 1; a < A; ++a) mx = fmaxf(mx, leaves[tid * A + a]);
        float e[A];
        float sum = 0.f;
        for (int a = 0; a < A; ++a) { e[a] = expf(leaves[tid * A + a] - mx); sum += e[a]; }
        for (int a = 0; a < 9; ++a)
            shL2[tid][a] = make_float2(e[2 * a] / sum, e[2 * a + 1] / sum);
    }
    __syncthreads();
    if (tid < R) {
        float ssum = shG[tid * F + 0] + shG[tid * F + 1] + shG[tid * F + 2] + shG[tid * F + 3];
        shCond[tid] = (ssum > SMALL_NUM_F) ? 1.0f : 0.0f;
    }
}

// ---------------------------------------------------------------------------
// Main: per-block uniform header (K± collapse parallelized over 192 threads,
// f64, fixed reduction order) + fast path + compacted ambiguous list.
// With b1=b2=0 each (r,f) MLP is piecewise-linear in s_f with one kink at 0:
// dot = s_f * K(sign(s_f)) + b3.
// ---------------------------------------------------------------------------
template<bool USE_LIST>
__global__ __launch_bounds__(256) void ftc_main(
    const float* __restrict__ s,
    const float* __restrict__ W1, const float* __restrict__ b1,
    const float* __restrict__ W2, const float* __restrict__ b2,
    const float* __restrict__ W3, const float* __restrict__ b3,
    const float* __restrict__ p_select, const float* __restrict__ leaves,
    const float* __restrict__ gumbel,
    unsigned int* __restrict__ ws_count,
    unsigned int* __restrict__ list,
    float* __restrict__ out)
{
    __shared__ double shPp[R * F * H], shPm[R * F * H];
    __shared__ float shKP[R * F], shKM[R * F], shG[R * F], shB3[R * F];
    __shared__ float shCond[R];
    __shared__ float2 shL2[4][9];
    __shared__ int shNZ;
    __shared__ unsigned char sh_idx[256];

    const int tid = threadIdx.x;
    if (tid == 0) shNZ = 0;
    __syncthreads();

    // --- header phase ---
    if (tid < R * F * H) {
        if (b1[tid] != 0.0f || b2[tid] != 0.0f) atomicOr(&shNZ, 1);
        // (rf, o) pair: per-o contribution to K± in f64
        const int rf = tid >> 4, o = tid & 15;
        double Pp = 0.0, Pm = 0.0;
        for (int h = 0; h < H; ++h) {
            const double w1 = (double)W1[rf * H + h];
            const double w2 = (double)W2[rf * H * H + h * H + o];
            Pp += w1 * ((w1 > 0.0) ? 1.0 : 0.01) * w2;
            Pm += w1 * ((w1 < 0.0) ? 1.0 : 0.01) * w2;
        }
        const double w3 = (double)W3[rf * H + o];
        shPp[tid] = Pp * ((Pp > 0.0) ? 1.0 : 0.01) * w3;
        shPm[tid] = Pm * ((Pm < 0.0) ? 1.0 : 0.01) * w3;
    }
    block_compute_gumbel_leaves(p_select, gumbel, leaves, b3, tid,
                                shG, shB3, shCond, shL2);  // has one __syncthreads inside
    __syncthreads();
    if (tid < R * F) {   // fixed-order o-ascending reduction (deterministic)
        double Kp = 0.0, Km = 0.0;
        for (int o = 0; o < H; ++o) { Kp += shPp[tid * H + o]; Km += shPm[tid * H + o]; }
        shKP[tid] = (float)Kp;
        shKM[tid] = (float)Km;
    }
    __syncthreads();

    const int flag = (shNZ == 0) ? 1 : 0;

    const int b = blockIdx.x * 256 + tid;
    const float4 sv = *reinterpret_cast<const float4*>(s + (size_t)b * F);
    const float sf[F] = {sv.x, sv.y, sv.z, sv.w};

    float st[R] = {0.f, 0.f, 0.f};
    bool need_exact = true;

    if (flag) {
        // fast path: 1/m = min(1 + e^{-dot}, 1/0.015)
#pragma unroll
        for (int r = 0; r < R; ++r) {
            const bool c = shCond[r] != 0.0f;
            float num = 0.f, den = 0.f;
#pragma unroll
            for (int f = 0; f < F; ++f) {
                const int rf = r * F + f;
                const float k = (sf[f] > 0.0f) ? shKP[rf] : shKM[rf];
                const float dot = fmaf(sf[f], k, shB3[rf]);
                const float inv_m = fminf(1.0f + __expf(-dot), 1.0f / SMALL_NUM_F);
                const float mm = __builtin_amdgcn_rcpf(inv_m);
                const float g = shG[rf];
                float xw = __expf(0.1f * g * inv_m);
                if (c) xw *= g;
                num = fmaf(mm * xw, g, num);
                den += xw;
            }
            st[r] = num * __builtin_amdgcn_rcpf(den);
        }
        // top-2 margin of the 4 path probs; NaN-safe (NaN -> ambiguous)
        const float r0 = st[0], r1 = st[1], r2 = st[2];
        const float p0 = r0 * r1;
        const float p1 = r0 * (1.0f - r1);
        const float p2 = (1.0f - r0) * r2;
        const float p3 = (1.0f - r0) * (1.0f - r2);
        const float a = fmaxf(p0, p1), bb = fminf(p0, p1);
        const float c2 = fmaxf(p2, p3), d = fminf(p2, p3);
        const float best = fmaxf(a, c2);
        const float second = fmaxf(fminf(a, c2), (a >= c2) ? bb : d);
        need_exact = !((best - second) > MARGIN_TAU);
    }

    if constexpr (USE_LIST) {
        if (need_exact) {   // flag==1: ~1% ambiguous; flag==0: all elements
            unsigned int pos = atomicAdd(ws_count, 1u);
            list[pos] = (unsigned int)b;
        }
        // st placeholder (0,0,0) when flag==0 -> deterministic row, cleanup overwrites
    } else {
        if (need_exact) {   // no workspace: inline exact fallback (slow, correct)
            float g[R][F], cond[R], m[R][F];
#pragma unroll
            for (int r = 0; r < R; ++r) {
                cond[r] = shCond[r];
#pragma unroll
                for (int f = 0; f < F; ++f) g[r][f] = shG[r * F + f];
            }
            compute_m_exact(sf, W1, b1, W2, b2, W3, b3, m);
            compute_strength_exact(m, g, cond, st);
        }
    }

    sh_idx[tid] = (unsigned char)path_argmax(st);
    __syncthreads();

    // coalesced float2 output: 2304 float2 per block; 9 float2 per element
    float2* outb = reinterpret_cast<float2*>(out + (size_t)blockIdx.x * (256 * A));
    for (int j = tid; j < 256 * (A / 2); j += 256) {
        const int bl = j / 9;
        const int off = j - bl * 9;
        outb[j] = shL2[sh_idx[bl]][off];
    }
}

// ---------------------------------------------------------------------------
// Cleanup: dense compacted list; 16 lanes per flagged element; lane l<12 runs
// one (r,f) sub-MLP from LDS-staged weights (bit-exact op order vs
// compute_m_exact); m gathered via __shfl; strength/argmax redundant per lane.
// Header (g/cond/leaves/b3) recomputed in-block (verbatim ops).
// ---------------------------------------------------------------------------
#define W2S 260
__global__ __launch_bounds__(256) void ftc_cleanup(
    const float* __restrict__ s,
    const float* __restrict__ W1, const float* __restrict__ b1,
    const float* __restrict__ W2, const float* __restrict__ b2,
    const float* __restrict__ W3, const float* __restrict__ b3,
    const float* __restrict__ p_select, const float* __restrict__ leaves,
    const float* __restrict__ gumbel,
    const unsigned int* __restrict__ ws_count,
    const unsigned int* __restrict__ list,
    float* __restrict__ out)
{
    const int count = (int)*ws_count;
    if ((int)blockIdx.x * 16 >= count) return;   // uniform early-exit

    __shared__ float shW1[12 * 17], shB1[12 * 17], shB2[12 * 17], shW3[12 * 17];
    __shared__ float shW2[12 * W2S];
    __shared__ float shG[R * F], shB3[R * F], shCond[R];
    __shared__ float2 shL2[4][9];

    const int tid = threadIdx.x;
    for (int i = tid; i < 192; i += 256) {
        const int rf = i >> 4, k = i & 15;
        shW1[rf * 17 + k] = W1[i];
        shB1[rf * 17 + k] = b1[i];
        shB2[rf * 17 + k] = b2[i];
        shW3[rf * 17 + k] = W3[i];
    }
    for (int i = tid; i < 3072; i += 256) {
        const int rf = i >> 8, k = i & 255;
        shW2[rf * W2S + k] = W2[i];
    }
    block_compute_gumbel_leaves(p_select, gumbel, leaves, b3, tid,
                                shG, shB3, shCond, shL2);
    __syncthreads();

    const int l = tid & 15;
    const int g0 = blockIdx.x * 16 + (tid >> 4);

    for (int i = g0; i < count; i += gridDim.x * 16) {
        const int e = (int)list[i];
        float mval = 0.f;
        if (l < 12) {
            const int rf = l;
            const int f = rf & 3;
            const float sfv = s[(size_t)e * F + f];
            float h1[H];
#pragma unroll
            for (int h = 0; h < H; ++h) {
                float v = fmaf(sfv, shW1[rf * 17 + h], shB1[rf * 17 + h]);
                h1[h] = fmaxf(v, 0.01f * v);
            }
            float acc[H];
#pragma unroll
            for (int o = 0; o < H; ++o) acc[o] = shB2[rf * 17 + o];
#pragma unroll
            for (int h = 0; h < H; ++h) {
                const float hv = h1[h];
#pragma unroll
                for (int c4 = 0; c4 < 4; ++c4) {
                    const float4 w2v = *reinterpret_cast<const float4*>(
                        &shW2[rf * W2S + h * 16 + c4 * 4]);
                    acc[c4 * 4 + 0] = fmaf(hv, w2v.x, acc[c4 * 4 + 0]);
                    acc[c4 * 4 + 1] = fmaf(hv, w2v.y, acc[c4 * 4 + 1]);
                    acc[c4 * 4 + 2] = fmaf(hv, w2v.z, acc[c4 * 4 + 2]);
                    acc[c4 * 4 + 3] = fmaf(hv, w2v.w, acc[c4 * 4 + 3]);
                }
            }
            float dot = shB3[rf];
#pragma unroll
            for (int o = 0; o < H; ++o) {
                float v = fmaxf(acc[o], 0.01f * acc[o]);
                dot = fmaf(v, shW3[rf * 17 + o], dot);
            }
            float mm = 1.0f / (1.0f + expf(-dot));
            mval = fmaxf(mm, SMALL_NUM_F);
        }
        float m[R][F], g[R][F], cond[R], st[R];
#pragma unroll
        for (int j = 0; j < 12; ++j) {
            const float mv = __shfl(mval, j, 16);
            m[j >> 2][j & 3] = mv;
        }
#pragma unroll
        for (int r = 0; r < R; ++r) {
            cond[r] = shCond[r];
#pragma unroll
            for (int f = 0; f < F; ++f) g[r][f] = shG[r * F + f];
        }
        compute_strength_exact(m, g, cond, st);
        const int idx = path_argmax(st);
        const float* lrow = reinterpret_cast<const float*>(&shL2[idx][0]);
        for (int a = l; a < A; a += 16)
            out[(size_t)e * A + a] = lrow[a];
    }
}

extern "C" void kernel_launch(void* const* d_in, const int* in_sizes, int n_in,
                              void* d_out, int out_size, void* d_ws, size_t ws_size,
                              hipStream_t stream) {
    const float* s  = (const float*)d_in[0];
    const float* W1 = (const float*)d_in[1];
    const float* b1 = (const float*)d_in[2];
    const float* W2 = (const float*)d_in[3];
    const float* b2 = (const float*)d_in[4];
    const float* W3 = (const float*)d_in[5];
    const float* b3 = (const float*)d_in[6];
    const float* ps = (const float*)d_in[7];
    const float* lv = (const float*)d_in[8];
    const float* gn = (const float*)d_in[9];
    float* out = (float*)d_out;
    unsigned int* ws_count = (unsigned int*)d_ws;
    unsigned int* list = (unsigned int*)((char*)d_ws + WS_HDR_BYTES);
    const bool use_list = ws_size >= (size_t)WS_HDR_BYTES + sizeof(unsigned int) * (size_t)BTOT;

    if (use_list) {
        hipMemsetAsync(d_ws, 0, WS_HDR_BYTES, stream);   // zero atomic counter
        hipLaunchKernelGGL((ftc_main<true>), dim3(BTOT / 256), dim3(256), 0, stream,
                           s, W1, b1, W2, b2, W3, b3, ps, lv, gn, ws_count, list, out);
        hipLaunchKernelGGL(ftc_cleanup, dim3(1024), dim3(256), 0, stream,
                           s, W1, b1, W2, b2, W3, b3, ps, lv, gn, ws_count, list, out);
    } else {
        hipLaunchKernelGGL((ftc_main<false>), dim3(BTOT / 256), dim3(256), 0, stream,
                           s, W1, b1, W2, b2, W3, b3, ps, lv, gn,
                           (unsigned int*)nullptr, (unsigned int*)nullptr, out);
    }
}